// Round 5
// baseline (947.345 us; speedup 1.0000x reference)
//
#include <hip/hip_runtime.h>
#include <cstdint>

namespace {

typedef _Float16 f16_t;
typedef _Float16 f16x8 __attribute__((ext_vector_type(8)));
typedef _Float16 f16x4 __attribute__((ext_vector_type(4)));
typedef float    f32x4 __attribute__((ext_vector_type(4)));

constexpr int Bc = 4, Tc = 1024, Hc = 4, Dc = 256, DHc = 1024, Lc = 6, Vc = 256;
constexpr int HALFc = 512;
constexpr float EPS = 1e-5f;
constexpr long long T4q  = (long long)Tc * 4096;      // 4M (row stride of x/y per b)
constexpr long long TDq  = (long long)Tc * Dc;        // 256K
constexpr long long DTq  = (long long)Dc * Tc;        // 256K
constexpr long long HDDq = (long long)DHc * Dc;       // 256K
constexpr long long TBUFq = (long long)Bc * Tc * Dc;  // 1M (split-K slice)

__device__ __forceinline__ void gload16(const void* g, void* l) {
  __builtin_amdgcn_global_load_lds((const __attribute__((address_space(1))) void*)g,
                                   (__attribute__((address_space(3))) void*)l, 16, 0, 0);
}

// ---------------------------------------------------------------------------
// MFMA f16 GEMM. 128x128 tile, BK=64, 4 waves (2x2 of 64x64), 16x16x32 MFMA.
// 2-phase double-buffered schedule (T3-minimum): STAGE(tile t+1) is issued
// BEFORE compute(tile t); one barrier (vmcnt drain) per K-step, so global
// loads fly during the MFMA phase. BKMAJ staging uses the T14 async-split:
// global->reg issue before compute, packed ds_write after compute.
// BKMAJ=false: C[m,n] = sum_k A[m,k]*B[n,k]   (B k-contiguous, [N][K])
// BKMAJ=true : C[m,n] = sum_k A[m,k]*B[k,n]   (B k-major, [K][N], ld=ldb)
// LDS [2][128 rows][64 k], 16B-slot XOR swizzle (slot ^ row&7), staged via
// pre-swizzled GLOBAL source + linear LDS dest (both-sides involution).
// Batch: z = zb*4 + zh; per-operand element offsets zb*s?b + zh*s?h.
// EPI: 0 = f16, 1 = relu->f16, 2 = relu*aux->f16 (aux shares C offsets), 4 = fp32
// ---------------------------------------------------------------------------
template<int EPI, bool BKMAJ>
__global__ __launch_bounds__(256)
void gemm_f16(const f16_t* __restrict__ A, long long sAb, long long sAh,
              const f16_t* __restrict__ B, long long sBb, long long sBh,
              void* __restrict__ Cv, long long sCb, long long sCh,
              const f16_t* __restrict__ aux,
              int K, int lda, int ldb, int ldc)
{
  __shared__ __align__(16) f16_t As[2][128 * 64];
  __shared__ __align__(16) f16_t Bs[2][128 * 64];

  const int zb = blockIdx.z >> 2, zh = blockIdx.z & 3;
  A += zb * sAb + zh * sAh;
  B += zb * sBb + zh * sBh;
  const long long Coff = zb * sCb + zh * sCh;

  const int tid  = threadIdx.x;
  const int lane = tid & 63;
  const int wave = tid >> 6;
  const int wr = wave >> 1, wc = wave & 1;
  const int m0 = blockIdx.y * 128, n0 = blockIdx.x * 128;

  const int lrow  = tid >> 3;   // 0..31
  const int lslot = tid & 7;    // 16B slot in 128B row
  const int kp = tid & 31, g = tid >> 5;  // BKMAJ staging coords

  f32x4 acc[4][4] = {};
  const int nt = K >> 6;

  // ---- prologue: stage tile 0 into buffer 0 ----
  #pragma unroll
  for (int c = 0; c < 4; ++c) {
    const int row  = c * 32 + lrow;
    const int scol = (lslot ^ (row & 7)) << 3;
    gload16(A + (size_t)(m0 + row) * lda + scol, &As[0][(c * 256 + tid) * 8]);
  }
  if (!BKMAJ) {
    #pragma unroll
    for (int c = 0; c < 4; ++c) {
      const int row  = c * 32 + lrow;
      const int scol = (lslot ^ (row & 7)) << 3;
      gload16(B + (size_t)(n0 + row) * ldb + scol, &Bs[0][(c * 256 + tid) * 8]);
    }
  } else {
    const int k = kp * 2;
    #pragma unroll
    for (int p = 0; p < 2; ++p) {
      const int nb = p * 64 + g * 8;
      const f16x8 r0 = *(const f16x8*)(B + (size_t)k * ldb + n0 + nb);
      const f16x8 r1 = *(const f16x8*)(B + (size_t)(k + 1) * ldb + n0 + nb);
      #pragma unroll
      for (int j = 0; j < 8; ++j) {
        const int n = nb + j;
        union { f16_t h[2]; unsigned int u; } pk;
        pk.h[0] = r0[j]; pk.h[1] = r1[j];
        ((unsigned int*)&Bs[0][0])[n * 32 + (((kp >> 2) ^ (n & 7)) << 2) + (kp & 3)] = pk.u;
      }
    }
  }
  __syncthreads();

  int cur = 0;
  for (int t = 0; ; ++t) {
    const bool hasnext = (t + 1 < nt);
    f16x8 p00, p01, p10, p11;   // BKMAJ reg prefetch (scalars: no dyn indexing)

    // ---- issue STAGE for tile t+1 into buffer cur^1 (before compute) ----
    if (hasnext) {
      const int k1 = (t + 1) << 6;
      #pragma unroll
      for (int c = 0; c < 4; ++c) {
        const int row  = c * 32 + lrow;
        const int scol = (lslot ^ (row & 7)) << 3;
        gload16(A + (size_t)(m0 + row) * lda + k1 + scol,
                &As[cur ^ 1][(c * 256 + tid) * 8]);
      }
      if (!BKMAJ) {
        #pragma unroll
        for (int c = 0; c < 4; ++c) {
          const int row  = c * 32 + lrow;
          const int scol = (lslot ^ (row & 7)) << 3;
          gload16(B + (size_t)(n0 + row) * ldb + k1 + scol,
                  &Bs[cur ^ 1][(c * 256 + tid) * 8]);
        }
      } else {
        const int k = k1 + kp * 2;
        p00 = *(const f16x8*)(B + (size_t)k * ldb + n0 + g * 8);
        p01 = *(const f16x8*)(B + (size_t)(k + 1) * ldb + n0 + g * 8);
        p10 = *(const f16x8*)(B + (size_t)k * ldb + n0 + 64 + g * 8);
        p11 = *(const f16x8*)(B + (size_t)(k + 1) * ldb + n0 + 64 + g * 8);
      }
    }

    // ---- compute tile t from buffer cur ----
    #pragma unroll
    for (int ks = 0; ks < 2; ++ks) {
      f16x8 af[4], bf[4];
      #pragma unroll
      for (int m = 0; m < 4; ++m) {
        const int r  = wr * 64 + m * 16 + (lane & 15);
        const int sl = (ks * 4 + (lane >> 4)) ^ (r & 7);
        af[m] = *(const f16x8*)(&As[cur][r * 64 + sl * 8]);
      }
      #pragma unroll
      for (int n = 0; n < 4; ++n) {
        const int r  = wc * 64 + n * 16 + (lane & 15);
        const int sl = (ks * 4 + (lane >> 4)) ^ (r & 7);
        bf[n] = *(const f16x8*)(&Bs[cur][r * 64 + sl * 8]);
      }
      #pragma unroll
      for (int m = 0; m < 4; ++m)
        #pragma unroll
        for (int n = 0; n < 4; ++n)
          acc[m][n] = __builtin_amdgcn_mfma_f32_16x16x32_f16(af[m], bf[n], acc[m][n], 0, 0, 0);
    }

    if (!hasnext) break;

    // ---- BKMAJ: land prefetched B regs into LDS (after compute) ----
    if (BKMAJ) {
      #pragma unroll
      for (int j = 0; j < 8; ++j) {
        {
          const int n = g * 8 + j;
          union { f16_t h[2]; unsigned int u; } pk;
          pk.h[0] = p00[j]; pk.h[1] = p01[j];
          ((unsigned int*)&Bs[cur ^ 1][0])[n * 32 + (((kp >> 2) ^ (n & 7)) << 2) + (kp & 3)] = pk.u;
        }
        {
          const int n = 64 + g * 8 + j;
          union { f16_t h[2]; unsigned int u; } pk;
          pk.h[0] = p10[j]; pk.h[1] = p11[j];
          ((unsigned int*)&Bs[cur ^ 1][0])[n * 32 + (((kp >> 2) ^ (n & 7)) << 2) + (kp & 3)] = pk.u;
        }
      }
    }
    __syncthreads();   // drains vmcnt (staged tile landed) + lgkm (ds_writes)
    cur ^= 1;
  }

  // ---- epilogue. C/D frag: col = lane&15, row = (lane>>4)*4 + reg ----
  const int cr   = (lane >> 4) * 4;
  const int ccol = lane & 15;
  if (EPI == 4) {
    float* C = (float*)Cv + Coff;
    #pragma unroll
    for (int m = 0; m < 4; ++m)
      #pragma unroll
      for (int n = 0; n < 4; ++n)
        #pragma unroll
        for (int r = 0; r < 4; ++r)
          C[(long long)(m0 + wr * 64 + m * 16 + cr + r) * ldc
            + (n0 + wc * 64 + n * 16 + ccol)] = acc[m][n][r];
  } else {
    f16_t* C = (f16_t*)Cv + Coff;
    const f16_t* X = (EPI == 2) ? aux + Coff : nullptr;
    #pragma unroll
    for (int m = 0; m < 4; ++m)
      #pragma unroll
      for (int n = 0; n < 4; ++n)
        #pragma unroll
        for (int r = 0; r < 4; ++r) {
          const long long off = (long long)(m0 + wr * 64 + m * 16 + cr + r) * ldc
                                + (n0 + wc * 64 + n * 16 + ccol);
          float val = acc[m][n][r];
          if (EPI >= 1) val = fmaxf(val, 0.0f);
          if (EPI == 2) val *= (float)X[off];
          C[off] = (f16_t)val;
        }
  }
}

// fp32 [R][C] -> f16 [C][R], batched over z
__global__ __launch_bounds__(256)
void transpose_f32_f16(const float* __restrict__ in, f16_t* __restrict__ out,
                       int R, int C, long long sIn, long long sOut)
{
  __shared__ float tile[32][33];
  in  += (long long)blockIdx.z * sIn;
  out += (long long)blockIdx.z * sOut;
  const int c0 = blockIdx.x * 32, r0 = blockIdx.y * 32;
  const int tx = threadIdx.x & 31, ty = threadIdx.x >> 5;
  #pragma unroll
  for (int i = 0; i < 32; i += 8)
    tile[ty + i][tx] = in[(long long)(r0 + ty + i) * C + (c0 + tx)];
  __syncthreads();
  #pragma unroll
  for (int i = 0; i < 32; i += 8)
    out[(long long)(c0 + ty + i) * R + (r0 + tx)] = (f16_t)tile[tx][ty + i];
}

// f16 [R][C] -> f16 [C][R], batched over z
__global__ __launch_bounds__(256)
void transpose_f16(const f16_t* __restrict__ in, f16_t* __restrict__ out,
                   int R, int C, long long sIn, long long sOut)
{
  __shared__ f16_t tile[32][34];
  in  += (long long)blockIdx.z * sIn;
  out += (long long)blockIdx.z * sOut;
  const int c0 = blockIdx.x * 32, r0 = blockIdx.y * 32;
  const int tx = threadIdx.x & 31, ty = threadIdx.x >> 5;
  #pragma unroll
  for (int i = 0; i < 32; i += 8)
    tile[ty + i][tx] = in[(long long)(r0 + ty + i) * C + (c0 + tx)];
  __syncthreads();
  #pragma unroll
  for (int i = 0; i < 32; i += 8)
    out[(long long)(c0 + ty + i) * R + (r0 + tx)] = tile[tx][ty + i];
}

__global__ __launch_bounds__(256)
void init_tables(float* __restrict__ cosT, float* __restrict__ sinT)
{
  const int i = blockIdx.x * 256 + threadIdx.x;  // < T*512
  const int j = i & (HALFc - 1);
  const int t = i >> 9;
  const float inv = expf(-(float)j * (9.210340371976184f / 512.0f));  // ln(1e4)/512
  const float ang = (float)t * inv;
  cosT[i] = cosf(ang);
  sinT[i] = sinf(ang);
}

// RoPE over x_all [B*T][H*Dh]; pairs (e, e+512) within each head's 1024 block
__global__ __launch_bounds__(256)
void rope_f16(const f16_t* __restrict__ x, f16_t* __restrict__ xr,
              const float* __restrict__ cosT, const float* __restrict__ sinT)
{
  const int i   = blockIdx.x * 256 + threadIdx.x;  // < B*T*H*128
  const int e4  = i & 127;
  const int bth = i >> 7;          // bt*4 + h
  const int t   = (bth >> 2) & (Tc - 1);
  const f32x4 c = ((const f32x4*)cosT)[t * 128 + e4];
  const f32x4 s = ((const f32x4*)sinT)[t * 128 + e4];
  const long long base = (long long)(bth >> 2) * 4096 + (bth & 3) * DHc + e4 * 4;
  const f16x4 x0 = *(const f16x4*)(x + base);
  const f16x4 x1 = *(const f16x4*)(x + base + HALFc);
  f16x4 r0, r1;
  #pragma unroll
  for (int j = 0; j < 4; ++j) {
    const float a = (float)x0[j], b = (float)x1[j];
    r0[j] = (f16_t)(a * c[j] - b * s[j]);
    r1[j] = (f16_t)(b * c[j] + a * s[j]);
  }
  *(f16x4*)(xr + base) = r0;
  *(f16x4*)(xr + base + HALFc) = r1;
}

__device__ __forceinline__ void block_stats(float val, float* red, float& mean, float& inv_std)
{
  float s1 = val, s2 = val * val;
  #pragma unroll
  for (int o = 1; o < 64; o <<= 1) {
    s1 += __shfl_xor(s1, o);
    s2 += __shfl_xor(s2, o);
  }
  const int lane = threadIdx.x & 63;
  const int w = threadIdx.x >> 6;
  if (lane == 0) { red[w * 2] = s1; red[w * 2 + 1] = s2; }
  __syncthreads();
  s1 = red[0] + red[2] + red[4] + red[6];
  s2 = red[1] + red[3] + red[5] + red[7];
  mean = s1 * (1.0f / Dc);
  const float var = s2 * (1.0f / Dc) - mean * mean;
  inv_std = 1.0f / sqrtf(var + EPS);
  __syncthreads();
}

__global__ __launch_bounds__(256)
void embed_ln(const int* __restrict__ tokens, const float* __restrict__ emb,
              f16_t* __restrict__ v)
{
  __shared__ float red[8];
  const int row = blockIdx.x;
  const int d = threadIdx.x;
  const float val = emb[(long long)tokens[row] * Dc + d];
  float m, is;
  block_stats(val, red, m, is);
  v[(long long)row * Dc + d] = (f16_t)((val - m) * is);
}

// v = LN(v + LN(sum_{z<4} t_z)); t split-K slices fp32
__global__ __launch_bounds__(256)
void fuse_ln4(f16_t* __restrict__ v, const float* __restrict__ t)
{
  __shared__ float red[8];
  const long long row = blockIdx.x;
  const int d = threadIdx.x;
  const long long off = row * Dc + d;
  const float tv = t[off] + t[off + TBUFq] + t[off + 2 * TBUFq] + t[off + 3 * TBUFq];
  float m1, is1;
  block_stats(tv, red, m1, is1);
  const float u = (tv - m1) * is1;
  const float wv = (float)v[off] + u;
  float m2, is2;
  block_stats(wv, red, m2, is2);
  v[off] = (f16_t)((wv - m2) * is2);
}

}  // anonymous namespace

extern "C" void kernel_launch(void* const* d_in, const int* in_sizes, int n_in,
                              void* d_out, int out_size, void* d_ws, size_t ws_size,
                              hipStream_t stream)
{
  (void)in_sizes; (void)n_in; (void)out_size; (void)ws_size;
  const int*   tokens  = (const int*)d_in[0];
  const float* emb_w   = (const float*)d_in[1];
  const float* E       = (const float*)d_in[2];
  const float* Dx      = (const float*)d_in[3];
  const float* Dy      = (const float*)d_in[4];
  const float* readout = (const float*)d_in[5];
  float* out = (float*)d_out;

  // Workspace carve-up (~90 MB)
  char* w = (char*)d_ws;
  auto carve = [&](size_t bytes) { char* p = w; w += (bytes + 255) & ~(size_t)255; return p; };
  float* cosT = (float*)carve((size_t)Tc * HALFc * 4);        // 2 MB
  float* sinT = (float*)carve((size_t)Tc * HALFc * 4);        // 2 MB
  f16_t* v    = (f16_t*)carve((size_t)Bc * Tc * Dc * 2);      // 2 MB
  f16_t* vT   = (f16_t*)carve((size_t)Bc * Dc * Tc * 2);      // 2 MB
  f16_t* x    = (f16_t*)carve((size_t)Bc * Tc * 4096 * 2);    // 32 MB [B*T][H*Dh]
  f16_t* xr   = (f16_t*)carve((size_t)Bc * Tc * 4096 * 2);    // 32 MB (also y)
  f16_t* WT   = (f16_t*)carve((size_t)Bc * Dc * 4096 * 2);    // 8 MB [B][D][H*Dh]
  f16_t* a    = (f16_t*)carve((size_t)Bc * Tc * Hc * Dc * 2); // 8 MB [B*T][H*D]
  float* t    = (float*)carve((size_t)4 * TBUFq * 4);         // 16 MB (split-K slices)
  f16_t* DxT  = (f16_t*)carve((size_t)Hc * DHc * Dc * 2);     // 2 MB [H*Dh][D]
  f16_t* DyT  = (f16_t*)carve((size_t)Hc * DHc * Dc * 2);     // 2 MB [H][Dh][D]
  f16_t* ET   = (f16_t*)carve((size_t)Dc * Hc * DHc * 2);     // 2 MB [D][H*Dh]
  f16_t* RT   = (f16_t*)carve((size_t)Vc * Dc * 2);           // 128 KB

  // One-time prep
  transpose_f32_f16<<<dim3(32, 8, Hc), 256, 0, stream>>>(Dx, DxT, Dc, DHc, HDDq, HDDq);
  transpose_f32_f16<<<dim3(32, 8, Hc), 256, 0, stream>>>(Dy, DyT, Dc, DHc, HDDq, HDDq);
  transpose_f32_f16<<<dim3(8, 128, 1), 256, 0, stream>>>(E, ET, 4096, Dc, 0, 0);
  transpose_f32_f16<<<dim3(8, 8, 1), 256, 0, stream>>>(readout, RT, Dc, Vc, 0, 0);
  init_tables<<<(Tc * HALFc) / 256, 256, 0, stream>>>(cosT, sinT);
  embed_ln<<<Bc * Tc, 256, 0, stream>>>(tokens, emb_w, v);
  transpose_f16<<<dim3(8, 32, Bc), 256, 0, stream>>>(v, vT, Tc, Dc, TDq, DTq);

  for (int l = 0; l < Lc; ++l) {
    // 1) x = relu(v . DxT^T): [4096 x 4096], K=256 — all heads in one GEMM
    gemm_f16<1, false><<<dim3(32, 32, 1), 256, 0, stream>>>(
        v, 0, 0, DxT, 0, 0, x, 0, 0, nullptr, Dc, Dc, Dc, 4096);
    // 2) xr = RoPE(x)
    rope_f16<<<(Bc * Tc * Hc * 128) / 256, 256, 0, stream>>>(x, xr, cosT, sinT);
    // 3) WT[b] = vT[b] . xr[b]  (B k-major): [256 x 4096], K=T=1024, z=4
    gemm_f16<0, true><<<dim3(32, 2, 4), 256, 0, stream>>>(
        vT, 0, DTq, xr, 0, T4q, WT, 0, (long long)Dc * 4096, nullptr,
        Tc, Tc, 4096, 4096);
    // 4) a[b,:,h,:] = xr_bh . WT_bh^T: [1024 x 256], K=Dh=1024, z=16
    gemm_f16<0, false><<<dim3(2, 8, 16), 256, 0, stream>>>(
        xr, T4q, DHc, WT, (long long)Dc * 4096, DHc, a, (long long)Tc * 1024, Dc,
        nullptr, DHc, 4096, 4096, 1024);
    // 5) y = relu(a_h . DyT_h^T) * x: [4096 x 1024] per head, z=4 (y -> xr)
    gemm_f16<2, false><<<dim3(8, 32, 4), 256, 0, stream>>>(
        a, 0, Dc, DyT, 0, HDDq, xr, 0, DHc, x, Dc, 1024, Dc, 4096);
    // 6) t_z = y_h . ET_h^T: [4096 x 256] fp32, K=1024, split-K over heads z=4
    gemm_f16<4, false><<<dim3(2, 32, 4), 256, 0, stream>>>(
        xr, 0, DHc, ET, 0, DHc, t, 0, TBUFq, nullptr, DHc, 4096, 4096, Dc);
    // 7) v = LN(v + LN(sum_z t_z)); 8) refresh vT
    fuse_ln4<<<Bc * Tc, 256, 0, stream>>>(v, t);
    transpose_f16<<<dim3(8, 32, Bc), 256, 0, stream>>>(v, vT, Tc, Dc, TDq, DTq);
  }

  // out = v . RT^T: [4096 x 256] fp32, K=256
  gemm_f16<4, false><<<dim3(2, 32, 1), 256, 0, stream>>>(
      v, 0, 0, RT, 0, 0, out, 0, 0, nullptr, Dc, Dc, Dc, Vc);
}

// Round 6
// 929.859 us; speedup vs baseline: 1.0188x; 1.0188x over previous
//
#include <hip/hip_runtime.h>
#include <cstdint>

namespace {

typedef _Float16 f16_t;
typedef _Float16 f16x8 __attribute__((ext_vector_type(8)));
typedef _Float16 f16x4 __attribute__((ext_vector_type(4)));
typedef float    f32x4 __attribute__((ext_vector_type(4)));

constexpr int Bc = 4, Tc = 1024, Hc = 4, Dc = 256, DHc = 1024, Lc = 6, Vc = 256;
constexpr int HALFc = 512;
constexpr float EPS = 1e-5f;
constexpr long long T4q  = (long long)Tc * 4096;      // 4M (row stride of x/y per b)
constexpr long long TDq  = (long long)Tc * Dc;        // 256K
constexpr long long DTq  = (long long)Dc * Tc;        // 256K
constexpr long long HDDq = (long long)DHc * Dc;       // 256K
constexpr long long TBUFq = (long long)Bc * Tc * Dc;  // 1M (split-K slice)

__device__ __forceinline__ void gload16(const void* g, void* l) {
  __builtin_amdgcn_global_load_lds((const __attribute__((address_space(1))) void*)g,
                                   (__attribute__((address_space(3))) void*)l, 16, 0, 0);
}

// ---------------------------------------------------------------------------
// MFMA f16 GEMM. 128x128 tile, BK=64, 4 waves (2x2 of 64x64), 16x16x32 MFMA.
// PIPE=0: single-buffer 1-phase (32KB LDS -> 4-5 blocks/CU; relies on
//         inter-block overlap — best for grids >= 2 blocks/CU).
// PIPE=1: double-buffered 2-phase (64KB LDS): STAGE(t+1) issued BEFORE
//         compute(t), one barrier per K-step — for 1-block/CU grids where
//         there is no neighbor block to hide the drain behind.
// BKMAJ=false: C[m,n] = sum_k A[m,k]*B[n,k]   (B k-contiguous, [N][K])
// BKMAJ=true : C[m,n] = sum_k A[m,k]*B[k,n]   (B k-major, [K][N], ld=ldb)
//              staged via reg + packed ds_write (PIPE=1: T14 async-split).
// LDS [128 rows][64 k], 16B-slot XOR swizzle (slot ^ row&7), staged via
// pre-swizzled GLOBAL source + linear LDS dest (both-sides involution).
// Batch: z = zb*4 + zh; per-operand element offsets zb*s?b + zh*s?h.
// EPI: 0 = f16, 1 = relu->f16, 2 = relu*aux->f16 (aux shares C offsets), 4 = fp32
// ---------------------------------------------------------------------------
template<int EPI, bool BKMAJ, bool PIPE>
__global__ __launch_bounds__(256)
void gemm_f16(const f16_t* __restrict__ A, long long sAb, long long sAh,
              const f16_t* __restrict__ B, long long sBb, long long sBh,
              void* __restrict__ Cv, long long sCb, long long sCh,
              const f16_t* __restrict__ aux,
              int K, int lda, int ldb, int ldc)
{
  constexpr int NB = PIPE ? 2 : 1;
  __shared__ __align__(16) f16_t As[NB][128 * 64];
  __shared__ __align__(16) f16_t Bs[NB][128 * 64];

  const int zb = blockIdx.z >> 2, zh = blockIdx.z & 3;
  A += zb * sAb + zh * sAh;
  B += zb * sBb + zh * sBh;
  const long long Coff = zb * sCb + zh * sCh;

  const int tid  = threadIdx.x;
  const int lane = tid & 63;
  const int wave = tid >> 6;
  const int wr = wave >> 1, wc = wave & 1;
  const int m0 = blockIdx.y * 128, n0 = blockIdx.x * 128;

  const int lrow  = tid >> 3;   // 0..31
  const int lslot = tid & 7;    // 16B slot in 128B row
  const int kp = tid & 31, g = tid >> 5;  // BKMAJ staging coords

  f32x4 acc[4][4] = {};

  if constexpr (!PIPE) {
    // ---------------- 1-phase single-buffer ----------------
    for (int k0 = 0; k0 < K; k0 += 64) {
      #pragma unroll
      for (int c = 0; c < 4; ++c) {
        const int row  = c * 32 + lrow;
        const int scol = (lslot ^ (row & 7)) << 3;
        gload16(A + (size_t)(m0 + row) * lda + k0 + scol, &As[0][(c * 256 + tid) * 8]);
      }
      if (!BKMAJ) {
        #pragma unroll
        for (int c = 0; c < 4; ++c) {
          const int row  = c * 32 + lrow;
          const int scol = (lslot ^ (row & 7)) << 3;
          gload16(B + (size_t)(n0 + row) * ldb + k0 + scol, &Bs[0][(c * 256 + tid) * 8]);
        }
      } else {
        const int k = kp * 2;
        #pragma unroll
        for (int p = 0; p < 2; ++p) {
          const int nb = p * 64 + g * 8;
          const f16x8 r0 = *(const f16x8*)(B + (size_t)(k0 + k) * ldb + n0 + nb);
          const f16x8 r1 = *(const f16x8*)(B + (size_t)(k0 + k + 1) * ldb + n0 + nb);
          #pragma unroll
          for (int j = 0; j < 8; ++j) {
            const int n = nb + j;
            union { f16_t h[2]; unsigned int u; } pk;
            pk.h[0] = r0[j]; pk.h[1] = r1[j];
            ((unsigned int*)&Bs[0][0])[n * 32 + (((kp >> 2) ^ (n & 7)) << 2) + (kp & 3)] = pk.u;
          }
        }
      }
      __syncthreads();

      #pragma unroll
      for (int ks = 0; ks < 2; ++ks) {
        f16x8 af[4], bf[4];
        #pragma unroll
        for (int m = 0; m < 4; ++m) {
          const int r  = wr * 64 + m * 16 + (lane & 15);
          const int sl = (ks * 4 + (lane >> 4)) ^ (r & 7);
          af[m] = *(const f16x8*)(&As[0][r * 64 + sl * 8]);
        }
        #pragma unroll
        for (int n = 0; n < 4; ++n) {
          const int r  = wc * 64 + n * 16 + (lane & 15);
          const int sl = (ks * 4 + (lane >> 4)) ^ (r & 7);
          bf[n] = *(const f16x8*)(&Bs[0][r * 64 + sl * 8]);
        }
        #pragma unroll
        for (int m = 0; m < 4; ++m)
          #pragma unroll
          for (int n = 0; n < 4; ++n)
            acc[m][n] = __builtin_amdgcn_mfma_f32_16x16x32_f16(af[m], bf[n], acc[m][n], 0, 0, 0);
      }
      __syncthreads();
    }
  } else {
    // ---------------- 2-phase double-buffer ----------------
    const int nt = K >> 6;
    // prologue: stage tile 0 into buffer 0
    #pragma unroll
    for (int c = 0; c < 4; ++c) {
      const int row  = c * 32 + lrow;
      const int scol = (lslot ^ (row & 7)) << 3;
      gload16(A + (size_t)(m0 + row) * lda + scol, &As[0][(c * 256 + tid) * 8]);
    }
    if (!BKMAJ) {
      #pragma unroll
      for (int c = 0; c < 4; ++c) {
        const int row  = c * 32 + lrow;
        const int scol = (lslot ^ (row & 7)) << 3;
        gload16(B + (size_t)(n0 + row) * ldb + scol, &Bs[0][(c * 256 + tid) * 8]);
      }
    } else {
      const int k = kp * 2;
      #pragma unroll
      for (int p = 0; p < 2; ++p) {
        const int nb = p * 64 + g * 8;
        const f16x8 r0 = *(const f16x8*)(B + (size_t)k * ldb + n0 + nb);
        const f16x8 r1 = *(const f16x8*)(B + (size_t)(k + 1) * ldb + n0 + nb);
        #pragma unroll
        for (int j = 0; j < 8; ++j) {
          const int n = nb + j;
          union { f16_t h[2]; unsigned int u; } pk;
          pk.h[0] = r0[j]; pk.h[1] = r1[j];
          ((unsigned int*)&Bs[0][0])[n * 32 + (((kp >> 2) ^ (n & 7)) << 2) + (kp & 3)] = pk.u;
        }
      }
    }
    __syncthreads();

    int cur = 0;
    for (int t = 0; ; ++t) {
      const bool hasnext = (t + 1 < nt);
      f16x8 p00, p01, p10, p11;   // BKMAJ reg prefetch

      if (hasnext) {
        const int k1 = (t + 1) << 6;
        #pragma unroll
        for (int c = 0; c < 4; ++c) {
          const int row  = c * 32 + lrow;
          const int scol = (lslot ^ (row & 7)) << 3;
          gload16(A + (size_t)(m0 + row) * lda + k1 + scol,
                  &As[cur ^ 1][(c * 256 + tid) * 8]);
        }
        if (!BKMAJ) {
          #pragma unroll
          for (int c = 0; c < 4; ++c) {
            const int row  = c * 32 + lrow;
            const int scol = (lslot ^ (row & 7)) << 3;
            gload16(B + (size_t)(n0 + row) * ldb + k1 + scol,
                    &Bs[cur ^ 1][(c * 256 + tid) * 8]);
          }
        } else {
          const int k = k1 + kp * 2;
          p00 = *(const f16x8*)(B + (size_t)k * ldb + n0 + g * 8);
          p01 = *(const f16x8*)(B + (size_t)(k + 1) * ldb + n0 + g * 8);
          p10 = *(const f16x8*)(B + (size_t)k * ldb + n0 + 64 + g * 8);
          p11 = *(const f16x8*)(B + (size_t)(k + 1) * ldb + n0 + 64 + g * 8);
        }
      }

      #pragma unroll
      for (int ks = 0; ks < 2; ++ks) {
        f16x8 af[4], bf[4];
        #pragma unroll
        for (int m = 0; m < 4; ++m) {
          const int r  = wr * 64 + m * 16 + (lane & 15);
          const int sl = (ks * 4 + (lane >> 4)) ^ (r & 7);
          af[m] = *(const f16x8*)(&As[cur][r * 64 + sl * 8]);
        }
        #pragma unroll
        for (int n = 0; n < 4; ++n) {
          const int r  = wc * 64 + n * 16 + (lane & 15);
          const int sl = (ks * 4 + (lane >> 4)) ^ (r & 7);
          bf[n] = *(const f16x8*)(&Bs[cur][r * 64 + sl * 8]);
        }
        #pragma unroll
        for (int m = 0; m < 4; ++m)
          #pragma unroll
          for (int n = 0; n < 4; ++n)
            acc[m][n] = __builtin_amdgcn_mfma_f32_16x16x32_f16(af[m], bf[n], acc[m][n], 0, 0, 0);
      }

      if (!hasnext) break;

      if (BKMAJ) {
        #pragma unroll
        for (int j = 0; j < 8; ++j) {
          {
            const int n = g * 8 + j;
            union { f16_t h[2]; unsigned int u; } pk;
            pk.h[0] = p00[j]; pk.h[1] = p01[j];
            ((unsigned int*)&Bs[cur ^ 1][0])[n * 32 + (((kp >> 2) ^ (n & 7)) << 2) + (kp & 3)] = pk.u;
          }
          {
            const int n = 64 + g * 8 + j;
            union { f16_t h[2]; unsigned int u; } pk;
            pk.h[0] = p10[j]; pk.h[1] = p11[j];
            ((unsigned int*)&Bs[cur ^ 1][0])[n * 32 + (((kp >> 2) ^ (n & 7)) << 2) + (kp & 3)] = pk.u;
          }
        }
      }
      __syncthreads();
      cur ^= 1;
    }
  }

  // ---- epilogue. C/D frag: col = lane&15, row = (lane>>4)*4 + reg ----
  const int cr   = (lane >> 4) * 4;
  const int ccol = lane & 15;
  if (EPI == 4) {
    float* C = (float*)Cv + Coff;
    #pragma unroll
    for (int m = 0; m < 4; ++m)
      #pragma unroll
      for (int n = 0; n < 4; ++n)
        #pragma unroll
        for (int r = 0; r < 4; ++r)
          C[(long long)(m0 + wr * 64 + m * 16 + cr + r) * ldc
            + (n0 + wc * 64 + n * 16 + ccol)] = acc[m][n][r];
  } else {
    f16_t* C = (f16_t*)Cv + Coff;
    const f16_t* X = (EPI == 2) ? aux + Coff : nullptr;
    #pragma unroll
    for (int m = 0; m < 4; ++m)
      #pragma unroll
      for (int n = 0; n < 4; ++n)
        #pragma unroll
        for (int r = 0; r < 4; ++r) {
          const long long off = (long long)(m0 + wr * 64 + m * 16 + cr + r) * ldc
                                + (n0 + wc * 64 + n * 16 + ccol);
          float val = acc[m][n][r];
          if (EPI >= 1) val = fmaxf(val, 0.0f);
          if (EPI == 2) val *= (float)X[off];
          C[off] = (f16_t)val;
        }
  }
}

// fp32 [R][C] -> f16 [C][R], batched over z
__global__ __launch_bounds__(256)
void transpose_f32_f16(const float* __restrict__ in, f16_t* __restrict__ out,
                       int R, int C, long long sIn, long long sOut)
{
  __shared__ float tile[32][33];
  in  += (long long)blockIdx.z * sIn;
  out += (long long)blockIdx.z * sOut;
  const int c0 = blockIdx.x * 32, r0 = blockIdx.y * 32;
  const int tx = threadIdx.x & 31, ty = threadIdx.x >> 5;
  #pragma unroll
  for (int i = 0; i < 32; i += 8)
    tile[ty + i][tx] = in[(long long)(r0 + ty + i) * C + (c0 + tx)];
  __syncthreads();
  #pragma unroll
  for (int i = 0; i < 32; i += 8)
    out[(long long)(c0 + ty + i) * R + (r0 + tx)] = (f16_t)tile[tx][ty + i];
}

// f16 [R][C] -> f16 [C][R], batched over z
__global__ __launch_bounds__(256)
void transpose_f16(const f16_t* __restrict__ in, f16_t* __restrict__ out,
                   int R, int C, long long sIn, long long sOut)
{
  __shared__ f16_t tile[32][34];
  in  += (long long)blockIdx.z * sIn;
  out += (long long)blockIdx.z * sOut;
  const int c0 = blockIdx.x * 32, r0 = blockIdx.y * 32;
  const int tx = threadIdx.x & 31, ty = threadIdx.x >> 5;
  #pragma unroll
  for (int i = 0; i < 32; i += 8)
    tile[ty + i][tx] = in[(long long)(r0 + ty + i) * C + (c0 + tx)];
  __syncthreads();
  #pragma unroll
  for (int i = 0; i < 32; i += 8)
    out[(long long)(c0 + ty + i) * R + (r0 + tx)] = tile[tx][ty + i];
}

__global__ __launch_bounds__(256)
void init_tables(float* __restrict__ cosT, float* __restrict__ sinT)
{
  const int i = blockIdx.x * 256 + threadIdx.x;  // < T*512
  const int j = i & (HALFc - 1);
  const int t = i >> 9;
  const float inv = expf(-(float)j * (9.210340371976184f / 512.0f));  // ln(1e4)/512
  const float ang = (float)t * inv;
  cosT[i] = cosf(ang);
  sinT[i] = sinf(ang);
}

// RoPE over x_all [B*T][H*Dh]; pairs (e, e+512) within each head's 1024 block
__global__ __launch_bounds__(256)
void rope_f16(const f16_t* __restrict__ x, f16_t* __restrict__ xr,
              const float* __restrict__ cosT, const float* __restrict__ sinT)
{
  const int i   = blockIdx.x * 256 + threadIdx.x;  // < B*T*H*128
  const int e4  = i & 127;
  const int bth = i >> 7;          // bt*4 + h
  const int t   = (bth >> 2) & (Tc - 1);
  const f32x4 c = ((const f32x4*)cosT)[t * 128 + e4];
  const f32x4 s = ((const f32x4*)sinT)[t * 128 + e4];
  const long long base = (long long)(bth >> 2) * 4096 + (bth & 3) * DHc + e4 * 4;
  const f16x4 x0 = *(const f16x4*)(x + base);
  const f16x4 x1 = *(const f16x4*)(x + base + HALFc);
  f16x4 r0, r1;
  #pragma unroll
  for (int j = 0; j < 4; ++j) {
    const float a = (float)x0[j], b = (float)x1[j];
    r0[j] = (f16_t)(a * c[j] - b * s[j]);
    r1[j] = (f16_t)(b * c[j] + a * s[j]);
  }
  *(f16x4*)(xr + base) = r0;
  *(f16x4*)(xr + base + HALFc) = r1;
}

__device__ __forceinline__ void block_stats(float val, float* red, float& mean, float& inv_std)
{
  float s1 = val, s2 = val * val;
  #pragma unroll
  for (int o = 1; o < 64; o <<= 1) {
    s1 += __shfl_xor(s1, o);
    s2 += __shfl_xor(s2, o);
  }
  const int lane = threadIdx.x & 63;
  const int w = threadIdx.x >> 6;
  if (lane == 0) { red[w * 2] = s1; red[w * 2 + 1] = s2; }
  __syncthreads();
  s1 = red[0] + red[2] + red[4] + red[6];
  s2 = red[1] + red[3] + red[5] + red[7];
  mean = s1 * (1.0f / Dc);
  const float var = s2 * (1.0f / Dc) - mean * mean;
  inv_std = 1.0f / sqrtf(var + EPS);
  __syncthreads();
}

__global__ __launch_bounds__(256)
void embed_ln(const int* __restrict__ tokens, const float* __restrict__ emb,
              f16_t* __restrict__ v)
{
  __shared__ float red[8];
  const int row = blockIdx.x;
  const int d = threadIdx.x;
  const float val = emb[(long long)tokens[row] * Dc + d];
  float m, is;
  block_stats(val, red, m, is);
  v[(long long)row * Dc + d] = (f16_t)((val - m) * is);
}

// v = LN(v + LN(sum_{z<4} t_z)); t split-K slices fp32
__global__ __launch_bounds__(256)
void fuse_ln4(f16_t* __restrict__ v, const float* __restrict__ t)
{
  __shared__ float red[8];
  const long long row = blockIdx.x;
  const int d = threadIdx.x;
  const long long off = row * Dc + d;
  const float tv = t[off] + t[off + TBUFq] + t[off + 2 * TBUFq] + t[off + 3 * TBUFq];
  float m1, is1;
  block_stats(tv, red, m1, is1);
  const float u = (tv - m1) * is1;
  const float wv = (float)v[off] + u;
  float m2, is2;
  block_stats(wv, red, m2, is2);
  v[off] = (f16_t)((wv - m2) * is2);
}

}  // anonymous namespace

extern "C" void kernel_launch(void* const* d_in, const int* in_sizes, int n_in,
                              void* d_out, int out_size, void* d_ws, size_t ws_size,
                              hipStream_t stream)
{
  (void)in_sizes; (void)n_in; (void)out_size; (void)ws_size;
  const int*   tokens  = (const int*)d_in[0];
  const float* emb_w   = (const float*)d_in[1];
  const float* E       = (const float*)d_in[2];
  const float* Dx      = (const float*)d_in[3];
  const float* Dy      = (const float*)d_in[4];
  const float* readout = (const float*)d_in[5];
  float* out = (float*)d_out;

  // Workspace carve-up (~90 MB)
  char* w = (char*)d_ws;
  auto carve = [&](size_t bytes) { char* p = w; w += (bytes + 255) & ~(size_t)255; return p; };
  float* cosT = (float*)carve((size_t)Tc * HALFc * 4);        // 2 MB
  float* sinT = (float*)carve((size_t)Tc * HALFc * 4);        // 2 MB
  f16_t* v    = (f16_t*)carve((size_t)Bc * Tc * Dc * 2);      // 2 MB
  f16_t* vT   = (f16_t*)carve((size_t)Bc * Dc * Tc * 2);      // 2 MB
  f16_t* x    = (f16_t*)carve((size_t)Bc * Tc * 4096 * 2);    // 32 MB [B*T][H*Dh]
  f16_t* xr   = (f16_t*)carve((size_t)Bc * Tc * 4096 * 2);    // 32 MB (also y)
  f16_t* WT   = (f16_t*)carve((size_t)Bc * Dc * 4096 * 2);    // 8 MB [B][D][H*Dh]
  f16_t* a    = (f16_t*)carve((size_t)Bc * Tc * Hc * Dc * 2); // 8 MB [B*T][H*D]
  float* t    = (float*)carve((size_t)4 * TBUFq * 4);         // 16 MB (split-K slices)
  f16_t* DxT  = (f16_t*)carve((size_t)Hc * DHc * Dc * 2);     // 2 MB [H*Dh][D]
  f16_t* DyT  = (f16_t*)carve((size_t)Hc * DHc * Dc * 2);     // 2 MB [H][Dh][D]
  f16_t* ET   = (f16_t*)carve((size_t)Dc * Hc * DHc * 2);     // 2 MB [D][H*Dh]
  f16_t* RT   = (f16_t*)carve((size_t)Vc * Dc * 2);           // 128 KB

  // One-time prep
  transpose_f32_f16<<<dim3(32, 8, Hc), 256, 0, stream>>>(Dx, DxT, Dc, DHc, HDDq, HDDq);
  transpose_f32_f16<<<dim3(32, 8, Hc), 256, 0, stream>>>(Dy, DyT, Dc, DHc, HDDq, HDDq);
  transpose_f32_f16<<<dim3(8, 128, 1), 256, 0, stream>>>(E, ET, 4096, Dc, 0, 0);
  transpose_f32_f16<<<dim3(8, 8, 1), 256, 0, stream>>>(readout, RT, Dc, Vc, 0, 0);
  init_tables<<<(Tc * HALFc) / 256, 256, 0, stream>>>(cosT, sinT);
  embed_ln<<<Bc * Tc, 256, 0, stream>>>(tokens, emb_w, v);
  transpose_f16<<<dim3(8, 32, Bc), 256, 0, stream>>>(v, vT, Tc, Dc, TDq, DTq);

  for (int l = 0; l < Lc; ++l) {
    // 1) x = relu(v . DxT^T): [4096 x 4096], K=256 — 1024 blocks -> PIPE=0
    gemm_f16<1, false, false><<<dim3(32, 32, 1), 256, 0, stream>>>(
        v, 0, 0, DxT, 0, 0, x, 0, 0, nullptr, Dc, Dc, Dc, 4096);
    // 2) xr = RoPE(x)
    rope_f16<<<(Bc * Tc * Hc * 128) / 256, 256, 0, stream>>>(x, xr, cosT, sinT);
    // 3) WT[b] = vT[b] . xr[b]: [256 x 4096], K=1024, z=4 — 256 blocks -> PIPE=1
    gemm_f16<0, true, true><<<dim3(32, 2, 4), 256, 0, stream>>>(
        vT, 0, DTq, xr, 0, T4q, WT, 0, (long long)Dc * 4096, nullptr,
        Tc, Tc, 4096, 4096);
    // 4) a[b,:,h,:] = xr_bh . WT_bh^T: [1024 x 256], K=1024, z=16 — 256 blocks -> PIPE=1
    gemm_f16<0, false, true><<<dim3(2, 8, 16), 256, 0, stream>>>(
        xr, T4q, DHc, WT, (long long)Dc * 4096, DHc, a, (long long)Tc * 1024, Dc,
        nullptr, DHc, 4096, 4096, 1024);
    // 5) y = relu(a_h . DyT_h^T) * x: [4096 x 1024], z=4 — 1024 blocks -> PIPE=0
    gemm_f16<2, false, false><<<dim3(8, 32, 4), 256, 0, stream>>>(
        a, 0, Dc, DyT, 0, HDDq, xr, 0, DHc, x, Dc, 1024, Dc, 4096);
    // 6) t_z = y_h . ET_h^T: [4096 x 256] fp32, K=1024, z=4 — 256 blocks -> PIPE=1
    gemm_f16<4, false, true><<<dim3(2, 32, 4), 256, 0, stream>>>(
        xr, 0, DHc, ET, 0, DHc, t, 0, TBUFq, nullptr, DHc, 4096, 4096, Dc);
    // 7) v = LN(v + LN(sum_z t_z)); 8) refresh vT
    fuse_ln4<<<Bc * Tc, 256, 0, stream>>>(v, t);
    transpose_f16<<<dim3(8, 32, Bc), 256, 0, stream>>>(v, vT, Tc, Dc, TDq, DTq);
  }

  // out = v . RT^T: [4096 x 256] fp32, K=256 — 64 blocks, latency-bound -> PIPE=1
  gemm_f16<4, false, true><<<dim3(2, 32, 1), 256, 0, stream>>>(
      v, 0, 0, RT, 0, 0, out, 0, 0, nullptr, Dc, Dc, Dc, Vc);
}

// Round 7
// 823.622 us; speedup vs baseline: 1.1502x; 1.1290x over previous
//
#include <hip/hip_runtime.h>
#include <cstdint>

namespace {

typedef _Float16 f16_t;
typedef _Float16 f16x8 __attribute__((ext_vector_type(8)));
typedef _Float16 f16x4 __attribute__((ext_vector_type(4)));
typedef float    f32x4 __attribute__((ext_vector_type(4)));

constexpr int Bc = 4, Tc = 1024, Hc = 4, Dc = 256, DHc = 1024, Lc = 6, Vc = 256;
constexpr int HALFc = 512;
constexpr float EPS = 1e-5f;
constexpr long long T4q  = (long long)Tc * 4096;      // 4M (row stride of x/y per b)
constexpr long long TDq  = (long long)Tc * Dc;        // 256K
constexpr long long DTq  = (long long)Dc * Tc;        // 256K
constexpr long long HDDq = (long long)DHc * Dc;       // 256K
constexpr long long TBUFq = (long long)Bc * Tc * Dc;  // 1M (split-K slice)

__device__ __forceinline__ void gload16(const void* g, void* l) {
  __builtin_amdgcn_global_load_lds((const __attribute__((address_space(1))) void*)g,
                                   (__attribute__((address_space(3))) void*)l, 16, 0, 0);
}

// ---------------------------------------------------------------------------
// MFMA f16 GEMM. 128x128 tile, BK=64, 16x16x32 MFMA, 1-phase single-buffer
// (inter-wave TLP hides staging latency — r5/r6 showed intra-block dbuf
// does not help at this tile size).
// NW = waves/block: 4 -> 2x2 waves of 64x64 (acc 4x4), 256 thr — for grids
//     with >=2 blocks/CU;  8 -> 2x4 waves of 64x32 (acc 4x2), 512 thr — for
//     256-block grids (1 block/CU) to get 2 waves/SIMD instead of 1.
// BKMAJ=false: C[m,n] = sum_k A[m,k]*B[n,k]   (B k-contiguous, [N][K])
// BKMAJ=true : C[m,n] = sum_k A[m,k]*B[k,n]   (B k-major, [K][N], ld=ldb)
//              staged via reg + packed ds_write.
// LDS [128 rows][64 k], 16B-slot XOR swizzle (slot ^ row&7), staged via
// pre-swizzled GLOBAL source + linear LDS dest (both-sides involution).
// Batch: z = zb*4 + zh; per-operand element offsets zb*s?b + zh*s?h.
// EPI: 0 = f16, 1 = relu->f16, 2 = relu*aux->f16 (aux shares C offsets), 4 = fp32
// ---------------------------------------------------------------------------
template<int EPI, bool BKMAJ, int NW>
__global__ __launch_bounds__(NW * 64)
void gemm_f16(const f16_t* __restrict__ A, long long sAb, long long sAh,
              const f16_t* __restrict__ B, long long sBb, long long sBh,
              void* __restrict__ Cv, long long sCb, long long sCh,
              const f16_t* __restrict__ aux,
              int K, int lda, int ldb, int ldc)
{
  constexpr int FN   = (NW == 4) ? 4 : 2;   // N-frags per wave
  constexpr int NTHR = NW * 64;
  constexpr int SP   = 1024 / NTHR;         // staging passes per 128-row tile
  constexpr int RPP  = NTHR / 8;            // rows per staging pass

  __shared__ __align__(16) f16_t As[128 * 64];
  __shared__ __align__(16) f16_t Bs[128 * 64];

  const int zb = blockIdx.z >> 2, zh = blockIdx.z & 3;
  A += zb * sAb + zh * sAh;
  B += zb * sBb + zh * sBh;
  const long long Coff = zb * sCb + zh * sCh;

  const int tid  = threadIdx.x;
  const int lane = tid & 63;
  const int wave = tid >> 6;
  const int wr = (NW == 4) ? (wave >> 1) : (wave >> 2);
  const int wc = (NW == 4) ? (wave & 1)  : (wave & 3);
  const int m0 = blockIdx.y * 128, n0 = blockIdx.x * 128;

  const int lrow  = tid >> 3;   // row within staging pass
  const int lslot = tid & 7;    // 16B slot in 128B row
  const int kp = tid & 31, g = tid >> 5;  // BKMAJ staging coords

  f32x4 acc[4][FN] = {};

  for (int k0 = 0; k0 < K; k0 += 64) {
    #pragma unroll
    for (int c = 0; c < SP; ++c) {
      const int row  = c * RPP + lrow;
      const int scol = (lslot ^ (row & 7)) << 3;
      gload16(A + (size_t)(m0 + row) * lda + k0 + scol, &As[(c * NTHR + tid) * 8]);
    }
    if (!BKMAJ) {
      #pragma unroll
      for (int c = 0; c < SP; ++c) {
        const int row  = c * RPP + lrow;
        const int scol = (lslot ^ (row & 7)) << 3;
        gload16(B + (size_t)(n0 + row) * ldb + k0 + scol, &Bs[(c * NTHR + tid) * 8]);
      }
    } else {
      // B from k-major [K][N]: thread (kp, g) packs k-pairs into b32 writes.
      // Cols covered per pass = (NTHR/32)*8; passes = 16/(NTHR/32/... ) = 512/NTHR*... 
      constexpr int NP = (NW == 4) ? 2 : 1;
      const int k = kp * 2;
      #pragma unroll
      for (int p = 0; p < NP; ++p) {
        const int nb = p * 64 + g * 8;
        const f16x8 r0 = *(const f16x8*)(B + (size_t)(k0 + k) * ldb + n0 + nb);
        const f16x8 r1 = *(const f16x8*)(B + (size_t)(k0 + k + 1) * ldb + n0 + nb);
        #pragma unroll
        for (int j = 0; j < 8; ++j) {
          const int n = nb + j;
          union { f16_t h[2]; unsigned int u; } pk;
          pk.h[0] = r0[j]; pk.h[1] = r1[j];
          ((unsigned int*)Bs)[n * 32 + (((kp >> 2) ^ (n & 7)) << 2) + (kp & 3)] = pk.u;
        }
      }
    }
    __syncthreads();

    #pragma unroll
    for (int ks = 0; ks < 2; ++ks) {
      f16x8 af[4], bf[FN];
      #pragma unroll
      for (int m = 0; m < 4; ++m) {
        const int r  = wr * 64 + m * 16 + (lane & 15);
        const int sl = (ks * 4 + (lane >> 4)) ^ (r & 7);
        af[m] = *(const f16x8*)(&As[r * 64 + sl * 8]);
      }
      #pragma unroll
      for (int n = 0; n < FN; ++n) {
        const int r  = wc * (FN * 16) + n * 16 + (lane & 15);
        const int sl = (ks * 4 + (lane >> 4)) ^ (r & 7);
        bf[n] = *(const f16x8*)(&Bs[r * 64 + sl * 8]);
      }
      #pragma unroll
      for (int m = 0; m < 4; ++m)
        #pragma unroll
        for (int n = 0; n < FN; ++n)
          acc[m][n] = __builtin_amdgcn_mfma_f32_16x16x32_f16(af[m], bf[n], acc[m][n], 0, 0, 0);
    }
    __syncthreads();
  }

  // ---- epilogue. C/D frag: col = lane&15, row = (lane>>4)*4 + reg ----
  const int cr   = (lane >> 4) * 4;
  const int ccol = lane & 15;
  if (EPI == 4) {
    float* C = (float*)Cv + Coff;
    #pragma unroll
    for (int m = 0; m < 4; ++m)
      #pragma unroll
      for (int n = 0; n < FN; ++n)
        #pragma unroll
        for (int r = 0; r < 4; ++r)
          C[(long long)(m0 + wr * 64 + m * 16 + cr + r) * ldc
            + (n0 + wc * (FN * 16) + n * 16 + ccol)] = acc[m][n][r];
  } else {
    f16_t* C = (f16_t*)Cv + Coff;
    const f16_t* X = (EPI == 2) ? aux + Coff : nullptr;
    #pragma unroll
    for (int m = 0; m < 4; ++m)
      #pragma unroll
      for (int n = 0; n < FN; ++n)
        #pragma unroll
        for (int r = 0; r < 4; ++r) {
          const long long off = (long long)(m0 + wr * 64 + m * 16 + cr + r) * ldc
                                + (n0 + wc * (FN * 16) + n * 16 + ccol);
          float val = acc[m][n][r];
          if (EPI >= 1) val = fmaxf(val, 0.0f);
          if (EPI == 2) val *= (float)X[off];
          C[off] = (f16_t)val;
        }
  }
}

// fp32 [R][C] -> f16 [C][R], batched over z
__global__ __launch_bounds__(256)
void transpose_f32_f16(const float* __restrict__ in, f16_t* __restrict__ out,
                       int R, int C, long long sIn, long long sOut)
{
  __shared__ float tile[32][33];
  in  += (long long)blockIdx.z * sIn;
  out += (long long)blockIdx.z * sOut;
  const int c0 = blockIdx.x * 32, r0 = blockIdx.y * 32;
  const int tx = threadIdx.x & 31, ty = threadIdx.x >> 5;
  #pragma unroll
  for (int i = 0; i < 32; i += 8)
    tile[ty + i][tx] = in[(long long)(r0 + ty + i) * C + (c0 + tx)];
  __syncthreads();
  #pragma unroll
  for (int i = 0; i < 32; i += 8)
    out[(long long)(c0 + ty + i) * R + (r0 + tx)] = (f16_t)tile[tx][ty + i];
}

// f16 [R][C] -> f16 [C][R], batched over z
__global__ __launch_bounds__(256)
void transpose_f16(const f16_t* __restrict__ in, f16_t* __restrict__ out,
                   int R, int C, long long sIn, long long sOut)
{
  __shared__ f16_t tile[32][34];
  in  += (long long)blockIdx.z * sIn;
  out += (long long)blockIdx.z * sOut;
  const int c0 = blockIdx.x * 32, r0 = blockIdx.y * 32;
  const int tx = threadIdx.x & 31, ty = threadIdx.x >> 5;
  #pragma unroll
  for (int i = 0; i < 32; i += 8)
    tile[ty + i][tx] = in[(long long)(r0 + ty + i) * C + (c0 + tx)];
  __syncthreads();
  #pragma unroll
  for (int i = 0; i < 32; i += 8)
    out[(long long)(c0 + ty + i) * R + (r0 + tx)] = tile[tx][ty + i];
}

__global__ __launch_bounds__(256)
void init_tables(float* __restrict__ cosT, float* __restrict__ sinT)
{
  const int i = blockIdx.x * 256 + threadIdx.x;  // < T*512
  const int j = i & (HALFc - 1);
  const int t = i >> 9;
  const float inv = expf(-(float)j * (9.210340371976184f / 512.0f));  // ln(1e4)/512
  const float ang = (float)t * inv;
  cosT[i] = cosf(ang);
  sinT[i] = sinf(ang);
}

// RoPE over x_all [B*T][H*Dh]; pairs (e, e+512) within each head's 1024 block
__global__ __launch_bounds__(256)
void rope_f16(const f16_t* __restrict__ x, f16_t* __restrict__ xr,
              const float* __restrict__ cosT, const float* __restrict__ sinT)
{
  const int i   = blockIdx.x * 256 + threadIdx.x;  // < B*T*H*128
  const int e4  = i & 127;
  const int bth = i >> 7;          // bt*4 + h
  const int t   = (bth >> 2) & (Tc - 1);
  const f32x4 c = ((const f32x4*)cosT)[t * 128 + e4];
  const f32x4 s = ((const f32x4*)sinT)[t * 128 + e4];
  const long long base = (long long)(bth >> 2) * 4096 + (bth & 3) * DHc + e4 * 4;
  const f16x4 x0 = *(const f16x4*)(x + base);
  const f16x4 x1 = *(const f16x4*)(x + base + HALFc);
  f16x4 r0, r1;
  #pragma unroll
  for (int j = 0; j < 4; ++j) {
    const float a = (float)x0[j], b = (float)x1[j];
    r0[j] = (f16_t)(a * c[j] - b * s[j]);
    r1[j] = (f16_t)(b * c[j] + a * s[j]);
  }
  *(f16x4*)(xr + base) = r0;
  *(f16x4*)(xr + base + HALFc) = r1;
}

__device__ __forceinline__ void block_stats(float val, float* red, float& mean, float& inv_std)
{
  float s1 = val, s2 = val * val;
  #pragma unroll
  for (int o = 1; o < 64; o <<= 1) {
    s1 += __shfl_xor(s1, o);
    s2 += __shfl_xor(s2, o);
  }
  const int lane = threadIdx.x & 63;
  const int w = threadIdx.x >> 6;
  if (lane == 0) { red[w * 2] = s1; red[w * 2 + 1] = s2; }
  __syncthreads();
  s1 = red[0] + red[2] + red[4] + red[6];
  s2 = red[1] + red[3] + red[5] + red[7];
  mean = s1 * (1.0f / Dc);
  const float var = s2 * (1.0f / Dc) - mean * mean;
  inv_std = 1.0f / sqrtf(var + EPS);
  __syncthreads();
}

__global__ __launch_bounds__(256)
void embed_ln(const int* __restrict__ tokens, const float* __restrict__ emb,
              f16_t* __restrict__ v)
{
  __shared__ float red[8];
  const int row = blockIdx.x;
  const int d = threadIdx.x;
  const float val = emb[(long long)tokens[row] * Dc + d];
  float m, is;
  block_stats(val, red, m, is);
  v[(long long)row * Dc + d] = (f16_t)((val - m) * is);
}

// v = LN(v + LN(sum_{z<4} t_z)); t split-K slices fp32
__global__ __launch_bounds__(256)
void fuse_ln4(f16_t* __restrict__ v, const float* __restrict__ t)
{
  __shared__ float red[8];
  const long long row = blockIdx.x;
  const int d = threadIdx.x;
  const long long off = row * Dc + d;
  const float tv = t[off] + t[off + TBUFq] + t[off + 2 * TBUFq] + t[off + 3 * TBUFq];
  float m1, is1;
  block_stats(tv, red, m1, is1);
  const float u = (tv - m1) * is1;
  const float wv = (float)v[off] + u;
  float m2, is2;
  block_stats(wv, red, m2, is2);
  v[off] = (f16_t)((wv - m2) * is2);
}

}  // anonymous namespace

extern "C" void kernel_launch(void* const* d_in, const int* in_sizes, int n_in,
                              void* d_out, int out_size, void* d_ws, size_t ws_size,
                              hipStream_t stream)
{
  (void)in_sizes; (void)n_in; (void)out_size; (void)ws_size;
  const int*   tokens  = (const int*)d_in[0];
  const float* emb_w   = (const float*)d_in[1];
  const float* E       = (const float*)d_in[2];
  const float* Dx      = (const float*)d_in[3];
  const float* Dy      = (const float*)d_in[4];
  const float* readout = (const float*)d_in[5];
  float* out = (float*)d_out;

  // Workspace carve-up (~90 MB)
  char* w = (char*)d_ws;
  auto carve = [&](size_t bytes) { char* p = w; w += (bytes + 255) & ~(size_t)255; return p; };
  float* cosT = (float*)carve((size_t)Tc * HALFc * 4);        // 2 MB
  float* sinT = (float*)carve((size_t)Tc * HALFc * 4);        // 2 MB
  f16_t* v    = (f16_t*)carve((size_t)Bc * Tc * Dc * 2);      // 2 MB
  f16_t* vT   = (f16_t*)carve((size_t)Bc * Dc * Tc * 2);      // 2 MB
  f16_t* x    = (f16_t*)carve((size_t)Bc * Tc * 4096 * 2);    // 32 MB [B*T][H*Dh]
  f16_t* xr   = (f16_t*)carve((size_t)Bc * Tc * 4096 * 2);    // 32 MB (also y)
  f16_t* WT   = (f16_t*)carve((size_t)Bc * Dc * 4096 * 2);    // 8 MB [B][D][H*Dh]
  f16_t* a    = (f16_t*)carve((size_t)Bc * Tc * Hc * Dc * 2); // 8 MB [B*T][H*D]
  float* t    = (float*)carve((size_t)4 * TBUFq * 4);         // 16 MB (split-K slices)
  f16_t* DxT  = (f16_t*)carve((size_t)Hc * DHc * Dc * 2);     // 2 MB [H*Dh][D]
  f16_t* DyT  = (f16_t*)carve((size_t)Hc * DHc * Dc * 2);     // 2 MB [H][Dh][D]
  f16_t* ET   = (f16_t*)carve((size_t)Dc * Hc * DHc * 2);     // 2 MB [D][H*Dh]
  f16_t* RT   = (f16_t*)carve((size_t)Vc * Dc * 2);           // 128 KB

  // One-time prep
  transpose_f32_f16<<<dim3(32, 8, Hc), 256, 0, stream>>>(Dx, DxT, Dc, DHc, HDDq, HDDq);
  transpose_f32_f16<<<dim3(32, 8, Hc), 256, 0, stream>>>(Dy, DyT, Dc, DHc, HDDq, HDDq);
  transpose_f32_f16<<<dim3(8, 128, 1), 256, 0, stream>>>(E, ET, 4096, Dc, 0, 0);
  transpose_f32_f16<<<dim3(8, 8, 1), 256, 0, stream>>>(readout, RT, Dc, Vc, 0, 0);
  init_tables<<<(Tc * HALFc) / 256, 256, 0, stream>>>(cosT, sinT);
  embed_ln<<<Bc * Tc, 256, 0, stream>>>(tokens, emb_w, v);
  transpose_f16<<<dim3(8, 32, Bc), 256, 0, stream>>>(v, vT, Tc, Dc, TDq, DTq);

  for (int l = 0; l < Lc; ++l) {
    // 1) x = relu(v . DxT^T): [4096 x 4096], K=256 — 1024 blocks -> NW=4
    gemm_f16<1, false, 4><<<dim3(32, 32, 1), 256, 0, stream>>>(
        v, 0, 0, DxT, 0, 0, x, 0, 0, nullptr, Dc, Dc, Dc, 4096);
    // 2) xr = RoPE(x)
    rope_f16<<<(Bc * Tc * Hc * 128) / 256, 256, 0, stream>>>(x, xr, cosT, sinT);
    // 3) WT[b] = vT[b] . xr[b]: [256 x 4096], K=1024, z=4 — 256 blocks -> NW=8
    gemm_f16<0, true, 8><<<dim3(32, 2, 4), 512, 0, stream>>>(
        vT, 0, DTq, xr, 0, T4q, WT, 0, (long long)Dc * 4096, nullptr,
        Tc, Tc, 4096, 4096);
    // 4) a[b,:,h,:] = xr_bh . WT_bh^T: [1024 x 256], K=1024, z=16 — 256 blocks -> NW=8
    gemm_f16<0, false, 8><<<dim3(2, 8, 16), 512, 0, stream>>>(
        xr, T4q, DHc, WT, (long long)Dc * 4096, DHc, a, (long long)Tc * 1024, Dc,
        nullptr, DHc, 4096, 4096, 1024);
    // 5) y = relu(a_h . DyT_h^T) * x: [4096 x 1024], z=4 — 1024 blocks -> NW=4
    gemm_f16<2, false, 4><<<dim3(8, 32, 4), 256, 0, stream>>>(
        a, 0, Dc, DyT, 0, HDDq, xr, 0, DHc, x, Dc, 1024, Dc, 4096);
    // 6) t_z = y_h . ET_h^T: [4096 x 256] fp32, K=1024, z=4 — 256 blocks -> NW=8
    gemm_f16<4, false, 8><<<dim3(2, 32, 4), 512, 0, stream>>>(
        xr, 0, DHc, ET, 0, DHc, t, 0, TBUFq, nullptr, DHc, 4096, 4096, Dc);
    // 7) v = LN(v + LN(sum_z t_z)); 8) refresh vT
    fuse_ln4<<<Bc * Tc, 256, 0, stream>>>(v, t);
    transpose_f16<<<dim3(8, 32, Bc), 256, 0, stream>>>(v, vT, Tc, Dc, TDq, DTq);
  }

  // out = v . RT^T: [4096 x 256] fp32, K=256 — 64 blocks -> NW=8
  gemm_f16<4, false, 8><<<dim3(2, 32, 1), 512, 0, stream>>>(
      v, 0, 0, RT, 0, 0, out, 0, 0, nullptr, Dc, Dc, Dc, Vc);
}

// Round 8
// 810.588 us; speedup vs baseline: 1.1687x; 1.0161x over previous
//
#include <hip/hip_runtime.h>
#include <cstdint>

namespace {

typedef _Float16 f16_t;
typedef _Float16 f16x8 __attribute__((ext_vector_type(8)));
typedef _Float16 f16x4 __attribute__((ext_vector_type(4)));
typedef float    f32x4 __attribute__((ext_vector_type(4)));

constexpr int Bc = 4, Tc = 1024, Hc = 4, Dc = 256, DHc = 1024, Lc = 6, Vc = 256;
constexpr int HALFc = 512;
constexpr float EPS = 1e-5f;
constexpr long long T4q  = (long long)Tc * 4096;      // 4M (row stride of x/y per b)
constexpr long long TDq  = (long long)Tc * Dc;        // 256K
constexpr long long DTq  = (long long)Dc * Tc;        // 256K
constexpr long long HDDq = (long long)DHc * Dc;       // 256K
constexpr long long TBUFq = (long long)Bc * Tc * Dc;  // 1M (split-K slice)

// Interleaved-pair permutation of the Dh axis: e -> 2*(e%512) + (e/512),
// applied within each head's 1024-block. RoPE pairs (e, e+512) become
// adjacent columns (2j, 2j+1) so RoPE fuses into gemm1's epilogue via
// __shfl_xor(.,1). Exact: the he axis is only contracted / elementwise /
// produced from (identically permuted) weight rows.
__device__ __forceinline__ int pe_perm(int v) {
  return (v & ~1023) | ((v & 511) << 1) | ((v >> 9) & 1);
}

__device__ __forceinline__ void gload16(const void* g, void* l) {
  __builtin_amdgcn_global_load_lds((const __attribute__((address_space(1))) void*)g,
                                   (__attribute__((address_space(3))) void*)l, 16, 0, 0);
}

// ---------------------------------------------------------------------------
// MFMA f16 GEMM. 128x128 tile, BK=64, 16x16x32 MFMA, 1-phase single-buffer
// (inter-wave TLP hides staging latency — r5/r6 showed intra-block dbuf
// does not help; r7 showed NW=8 is the lever for 1-block/CU grids).
// NW = waves/block: 4 -> 2x2 waves of 64x64 (acc 4x4), 256 thr;
//                   8 -> 2x4 waves of 64x32 (acc 4x2), 512 thr.
// BKMAJ=false: C[m,n] = sum_k A[m,k]*B[n,k]   (B k-contiguous, [N][K])
// BKMAJ=true : C[m,n] = sum_k A[m,k]*B[k,n]   (B k-major, [K][N], ld=ldb)
// LDS [128 rows][64 k], 16B-slot XOR swizzle (slot ^ row&7), staged via
// pre-swizzled GLOBAL source + linear LDS dest (both-sides involution).
// Batch: z = zb*4 + zh; per-operand element offsets zb*s?b + zh*s?h.
// EPI: 0 = f16, 1 = relu->f16, 2 = relu*aux->f16 (aux shares C offsets),
//      4 = fp32, 5 = relu->Cv AND RoPE(relu)->aux (dual f16 outputs; cols
//          are interleaved pairs; cosP/sinP are [T][512] f32 tables)
// ---------------------------------------------------------------------------
template<int EPI, bool BKMAJ, int NW>
__global__ __launch_bounds__(NW * 64)
void gemm_f16(const f16_t* __restrict__ A, long long sAb, long long sAh,
              const f16_t* __restrict__ B, long long sBb, long long sBh,
              void* __restrict__ Cv, long long sCb, long long sCh,
              const f16_t* __restrict__ aux,
              int K, int lda, int ldb, int ldc,
              const float* __restrict__ cosP, const float* __restrict__ sinP)
{
  constexpr int FN   = (NW == 4) ? 4 : 2;   // N-frags per wave
  constexpr int NTHR = NW * 64;
  constexpr int SP   = 1024 / NTHR;         // staging passes per 128-row tile
  constexpr int RPP  = NTHR / 8;            // rows per staging pass

  __shared__ __align__(16) f16_t As[128 * 64];
  __shared__ __align__(16) f16_t Bs[128 * 64];

  const int zb = blockIdx.z >> 2, zh = blockIdx.z & 3;
  A += zb * sAb + zh * sAh;
  B += zb * sBb + zh * sBh;
  const long long Coff = zb * sCb + zh * sCh;

  const int tid  = threadIdx.x;
  const int lane = tid & 63;
  const int wave = tid >> 6;
  const int wr = (NW == 4) ? (wave >> 1) : (wave >> 2);
  const int wc = (NW == 4) ? (wave & 1)  : (wave & 3);
  const int m0 = blockIdx.y * 128, n0 = blockIdx.x * 128;

  const int lrow  = tid >> 3;   // row within staging pass
  const int lslot = tid & 7;    // 16B slot in 128B row
  const int kp = tid & 31, g = tid >> 5;  // BKMAJ staging coords

  f32x4 acc[4][FN] = {};

  for (int k0 = 0; k0 < K; k0 += 64) {
    #pragma unroll
    for (int c = 0; c < SP; ++c) {
      const int row  = c * RPP + lrow;
      const int scol = (lslot ^ (row & 7)) << 3;
      gload16(A + (size_t)(m0 + row) * lda + k0 + scol, &As[(c * NTHR + tid) * 8]);
    }
    if (!BKMAJ) {
      #pragma unroll
      for (int c = 0; c < SP; ++c) {
        const int row  = c * RPP + lrow;
        const int scol = (lslot ^ (row & 7)) << 3;
        gload16(B + (size_t)(n0 + row) * ldb + k0 + scol, &Bs[(c * NTHR + tid) * 8]);
      }
    } else {
      constexpr int NP = (NW == 4) ? 2 : 1;
      const int k = kp * 2;
      #pragma unroll
      for (int p = 0; p < NP; ++p) {
        const int nb = p * 64 + g * 8;
        const f16x8 r0 = *(const f16x8*)(B + (size_t)(k0 + k) * ldb + n0 + nb);
        const f16x8 r1 = *(const f16x8*)(B + (size_t)(k0 + k + 1) * ldb + n0 + nb);
        #pragma unroll
        for (int j = 0; j < 8; ++j) {
          const int n = nb + j;
          union { f16_t h[2]; unsigned int u; } pk;
          pk.h[0] = r0[j]; pk.h[1] = r1[j];
          ((unsigned int*)Bs)[n * 32 + (((kp >> 2) ^ (n & 7)) << 2) + (kp & 3)] = pk.u;
        }
      }
    }
    __syncthreads();

    #pragma unroll
    for (int ks = 0; ks < 2; ++ks) {
      f16x8 af[4], bf[FN];
      #pragma unroll
      for (int m = 0; m < 4; ++m) {
        const int r  = wr * 64 + m * 16 + (lane & 15);
        const int sl = (ks * 4 + (lane >> 4)) ^ (r & 7);
        af[m] = *(const f16x8*)(&As[r * 64 + sl * 8]);
      }
      #pragma unroll
      for (int n = 0; n < FN; ++n) {
        const int r  = wc * (FN * 16) + n * 16 + (lane & 15);
        const int sl = (ks * 4 + (lane >> 4)) ^ (r & 7);
        bf[n] = *(const f16x8*)(&Bs[r * 64 + sl * 8]);
      }
      #pragma unroll
      for (int m = 0; m < 4; ++m)
        #pragma unroll
        for (int n = 0; n < FN; ++n)
          acc[m][n] = __builtin_amdgcn_mfma_f32_16x16x32_f16(af[m], bf[n], acc[m][n], 0, 0, 0);
    }
    __syncthreads();
  }

  // ---- epilogue. C/D frag: col = lane&15, row = (lane>>4)*4 + reg ----
  const int cr   = (lane >> 4) * 4;
  const int ccol = lane & 15;
  if (EPI == 4) {
    float* C = (float*)Cv + Coff;
    #pragma unroll
    for (int m = 0; m < 4; ++m)
      #pragma unroll
      for (int n = 0; n < FN; ++n)
        #pragma unroll
        for (int r = 0; r < 4; ++r)
          C[(long long)(m0 + wr * 64 + m * 16 + cr + r) * ldc
            + (n0 + wc * (FN * 16) + n * 16 + ccol)] = acc[m][n][r];
  } else if (EPI == 5) {
    // Dual output: x = relu(acc); xr = RoPE(x) with interleaved pair cols.
    f16_t* X  = (f16_t*)Cv;
    f16_t* XR = const_cast<f16_t*>(aux);
    #pragma unroll
    for (int m = 0; m < 4; ++m)
      #pragma unroll
      for (int n = 0; n < FN; ++n) {
        const int gcol = n0 + wc * (FN * 16) + n * 16 + ccol;
        const int jj   = (gcol & 1023) >> 1;
        const float sg = (gcol & 1) ? 1.0f : -1.0f;
        #pragma unroll
        for (int r = 0; r < 4; ++r) {
          const int grow = m0 + wr * 64 + m * 16 + cr + r;
          const int tt   = grow & (Tc - 1);
          const float val  = fmaxf(acc[m][n][r], 0.0f);
          const float part = __shfl_xor(val, 1);
          const float c = cosP[tt * HALFc + jj];
          const float s = sinP[tt * HALFc + jj];
          const float xrv = val * c + part * s * sg;
          const long long off = (long long)grow * ldc + gcol;
          X[off]  = (f16_t)val;
          XR[off] = (f16_t)xrv;
        }
      }
  } else {
    f16_t* C = (f16_t*)Cv + Coff;
    const f16_t* X = (EPI == 2) ? aux + Coff : nullptr;
    #pragma unroll
    for (int m = 0; m < 4; ++m)
      #pragma unroll
      for (int n = 0; n < FN; ++n)
        #pragma unroll
        for (int r = 0; r < 4; ++r) {
          const long long off = (long long)(m0 + wr * 64 + m * 16 + cr + r) * ldc
                                + (n0 + wc * (FN * 16) + n * 16 + ccol);
          float val = acc[m][n][r];
          if (EPI >= 1) val = fmaxf(val, 0.0f);
          if (EPI == 2) val *= (float)X[off];
          C[off] = (f16_t)val;
        }
  }
}

// fp32 [R][C] -> f16 [C][R], batched over z. permR/permC apply the
// interleaved-pair permutation to the output row / column index.
__global__ __launch_bounds__(256)
void transpose_f32_f16(const float* __restrict__ in, f16_t* __restrict__ out,
                       int R, int C, long long sIn, long long sOut,
                       int permR, int permC)
{
  __shared__ float tile[32][33];
  in  += (long long)blockIdx.z * sIn;
  out += (long long)blockIdx.z * sOut;
  const int c0 = blockIdx.x * 32, r0 = blockIdx.y * 32;
  const int tx = threadIdx.x & 31, ty = threadIdx.x >> 5;
  #pragma unroll
  for (int i = 0; i < 32; i += 8)
    tile[ty + i][tx] = in[(long long)(r0 + ty + i) * C + (c0 + tx)];
  __syncthreads();
  #pragma unroll
  for (int i = 0; i < 32; i += 8) {
    int ro = c0 + ty + i;
    int co = r0 + tx;
    if (permR) ro = pe_perm(ro);
    if (permC) co = pe_perm(co);
    out[(long long)ro * R + co] = (f16_t)tile[tx][ty + i];
  }
}

// f16 [R][C] -> f16 [C][R], batched over z
__global__ __launch_bounds__(256)
void transpose_f16(const f16_t* __restrict__ in, f16_t* __restrict__ out,
                   int R, int C, long long sIn, long long sOut)
{
  __shared__ f16_t tile[32][34];
  in  += (long long)blockIdx.z * sIn;
  out += (long long)blockIdx.z * sOut;
  const int c0 = blockIdx.x * 32, r0 = blockIdx.y * 32;
  const int tx = threadIdx.x & 31, ty = threadIdx.x >> 5;
  #pragma unroll
  for (int i = 0; i < 32; i += 8)
    tile[ty + i][tx] = in[(long long)(r0 + ty + i) * C + (c0 + tx)];
  __syncthreads();
  #pragma unroll
  for (int i = 0; i < 32; i += 8)
    out[(long long)(c0 + ty + i) * R + (r0 + tx)] = tile[tx][ty + i];
}

// cos/sin[t][j] = cos/sin(t * 10000^(-j/512)), j in [0,512)
__global__ __launch_bounds__(256)
void init_tables(float* __restrict__ cosT, float* __restrict__ sinT)
{
  const int i = blockIdx.x * 256 + threadIdx.x;  // < T*512
  const int j = i & (HALFc - 1);
  const int t = i >> 9;
  const float inv = expf(-(float)j * (9.210340371976184f / 512.0f));  // ln(1e4)/512
  const float ang = (float)t * inv;
  cosT[i] = cosf(ang);
  sinT[i] = sinf(ang);
}

__device__ __forceinline__ void block_stats(float val, float* red, float& mean, float& inv_std)
{
  float s1 = val, s2 = val * val;
  #pragma unroll
  for (int o = 1; o < 64; o <<= 1) {
    s1 += __shfl_xor(s1, o);
    s2 += __shfl_xor(s2, o);
  }
  const int lane = threadIdx.x & 63;
  const int w = threadIdx.x >> 6;
  if (lane == 0) { red[w * 2] = s1; red[w * 2 + 1] = s2; }
  __syncthreads();
  s1 = red[0] + red[2] + red[4] + red[6];
  s2 = red[1] + red[3] + red[5] + red[7];
  mean = s1 * (1.0f / Dc);
  const float var = s2 * (1.0f / Dc) - mean * mean;
  inv_std = 1.0f / sqrtf(var + EPS);
  __syncthreads();
}

__global__ __launch_bounds__(256)
void embed_ln(const int* __restrict__ tokens, const float* __restrict__ emb,
              f16_t* __restrict__ v)
{
  __shared__ float red[8];
  const int row = blockIdx.x;
  const int d = threadIdx.x;
  const float val = emb[(long long)tokens[row] * Dc + d];
  float m, is;
  block_stats(val, red, m, is);
  v[(long long)row * Dc + d] = (f16_t)((val - m) * is);
}

// v = LN(v + LN(sum_{z<4} t_z)); t split-K slices fp32
__global__ __launch_bounds__(256)
void fuse_ln4(f16_t* __restrict__ v, const float* __restrict__ t)
{
  __shared__ float red[8];
  const long long row = blockIdx.x;
  const int d = threadIdx.x;
  const long long off = row * Dc + d;
  const float tv = t[off] + t[off + TBUFq] + t[off + 2 * TBUFq] + t[off + 3 * TBUFq];
  float m1, is1;
  block_stats(tv, red, m1, is1);
  const float u = (tv - m1) * is1;
  const float wv = (float)v[off] + u;
  float m2, is2;
  block_stats(wv, red, m2, is2);
  v[off] = (f16_t)((wv - m2) * is2);
}

}  // anonymous namespace

extern "C" void kernel_launch(void* const* d_in, const int* in_sizes, int n_in,
                              void* d_out, int out_size, void* d_ws, size_t ws_size,
                              hipStream_t stream)
{
  (void)in_sizes; (void)n_in; (void)out_size; (void)ws_size;
  const int*   tokens  = (const int*)d_in[0];
  const float* emb_w   = (const float*)d_in[1];
  const float* E       = (const float*)d_in[2];
  const float* Dx      = (const float*)d_in[3];
  const float* Dy      = (const float*)d_in[4];
  const float* readout = (const float*)d_in[5];
  float* out = (float*)d_out;

  // Workspace carve-up (~90 MB)
  char* w = (char*)d_ws;
  auto carve = [&](size_t bytes) { char* p = w; w += (bytes + 255) & ~(size_t)255; return p; };
  float* cosT = (float*)carve((size_t)Tc * HALFc * 4);        // 2 MB
  float* sinT = (float*)carve((size_t)Tc * HALFc * 4);        // 2 MB
  f16_t* v    = (f16_t*)carve((size_t)Bc * Tc * Dc * 2);      // 2 MB
  f16_t* vT   = (f16_t*)carve((size_t)Bc * Dc * Tc * 2);      // 2 MB
  f16_t* x    = (f16_t*)carve((size_t)Bc * Tc * 4096 * 2);    // 32 MB [B*T][H*Dh]
  f16_t* xr   = (f16_t*)carve((size_t)Bc * Tc * 4096 * 2);    // 32 MB (also y)
  f16_t* WT   = (f16_t*)carve((size_t)Bc * Dc * 4096 * 2);    // 8 MB [B][D][H*Dh]
  f16_t* a    = (f16_t*)carve((size_t)Bc * Tc * Hc * Dc * 2); // 8 MB [B*T][H*D]
  float* t    = (float*)carve((size_t)4 * TBUFq * 4);         // 16 MB (split-K slices)
  f16_t* DxT  = (f16_t*)carve((size_t)Hc * DHc * Dc * 2);     // 2 MB [H*Dh][D] (perm rows)
  f16_t* DyT  = (f16_t*)carve((size_t)Hc * DHc * Dc * 2);     // 2 MB (perm rows)
  f16_t* ET   = (f16_t*)carve((size_t)Dc * Hc * DHc * 2);     // 2 MB [D][H*Dh] (perm cols)
  f16_t* RT   = (f16_t*)carve((size_t)Vc * Dc * 2);           // 128 KB

  // One-time prep (weights carry the interleaved-pair he permutation)
  transpose_f32_f16<<<dim3(32, 8, Hc), 256, 0, stream>>>(Dx, DxT, Dc, DHc, HDDq, HDDq, 1, 0);
  transpose_f32_f16<<<dim3(32, 8, Hc), 256, 0, stream>>>(Dy, DyT, Dc, DHc, HDDq, HDDq, 1, 0);
  transpose_f32_f16<<<dim3(8, 128, 1), 256, 0, stream>>>(E, ET, 4096, Dc, 0, 0, 0, 1);
  transpose_f32_f16<<<dim3(8, 8, 1), 256, 0, stream>>>(readout, RT, Dc, Vc, 0, 0, 0, 0);
  init_tables<<<(Tc * HALFc) / 256, 256, 0, stream>>>(cosT, sinT);
  embed_ln<<<Bc * Tc, 256, 0, stream>>>(tokens, emb_w, v);
  transpose_f16<<<dim3(8, 32, Bc), 256, 0, stream>>>(v, vT, Tc, Dc, TDq, DTq);

  for (int l = 0; l < Lc; ++l) {
    // 1) x = relu(v . DxT^T), xr = RoPE(x) fused: [4096 x 4096], K=256
    gemm_f16<5, false, 4><<<dim3(32, 32, 1), 256, 0, stream>>>(
        v, 0, 0, DxT, 0, 0, x, 0, 0, xr, Dc, Dc, Dc, 4096, cosT, sinT);
    // 3) WT[b] = vT[b] . xr[b]: [256 x 4096], K=1024, z=4 — NW=8
    gemm_f16<0, true, 8><<<dim3(32, 2, 4), 512, 0, stream>>>(
        vT, 0, DTq, xr, 0, T4q, WT, 0, (long long)Dc * 4096, nullptr,
        Tc, Tc, 4096, 4096, nullptr, nullptr);
    // 4) a[b,:,h,:] = xr_bh . WT_bh^T: [1024 x 256], K=1024, z=16 — NW=8
    gemm_f16<0, false, 8><<<dim3(2, 8, 16), 512, 0, stream>>>(
        xr, T4q, DHc, WT, (long long)Dc * 4096, DHc, a, (long long)Tc * 1024, Dc,
        nullptr, DHc, 4096, 4096, 1024, nullptr, nullptr);
    // 5) y = relu(a_h . DyT_h^T) * x: [4096 x 1024], z=4 — NW=4 (y -> xr)
    gemm_f16<2, false, 4><<<dim3(8, 32, 4), 256, 0, stream>>>(
        a, 0, Dc, DyT, 0, HDDq, xr, 0, DHc, x, Dc, 1024, Dc, 4096, nullptr, nullptr);
    // 6) t_z = y_h . ET_h^T: [4096 x 256] fp32, K=1024, z=4 — NW=8
    gemm_f16<4, false, 8><<<dim3(2, 32, 4), 512, 0, stream>>>(
        xr, 0, DHc, ET, 0, DHc, t, 0, TBUFq, nullptr, DHc, 4096, 4096, Dc,
        nullptr, nullptr);
    // 7) v = LN(v + LN(sum_z t_z)); 8) refresh vT
    fuse_ln4<<<Bc * Tc, 256, 0, stream>>>(v, t);
    transpose_f16<<<dim3(8, 32, Bc), 256, 0, stream>>>(v, vT, Tc, Dc, TDq, DTq);
  }

  // out = v . RT^T: [4096 x 256] fp32, K=256 — NW=8
  gemm_f16<4, false, 8><<<dim3(2, 32, 1), 512, 0, stream>>>(
      v, 0, 0, RT, 0, 0, out, 0, 0, nullptr, Dc, Dc, Dc, Vc, nullptr, nullptr);
}